// Round 2
// baseline (825.082 us; speedup 1.0000x reference)
//
#include <hip/hip_runtime.h>
#include <math.h>

// Problem constants (match reference)
constexpr int T1N  = 30000;
constexpr int T2N  = 8192;
constexpr int FIN  = 512;
constexpr int FHID = 256;
constexpr int FOUT = 20;

// ---------------------------------------------------------------------------
// CSR build: count -> exclusive scan -> bucket scatter
// ---------------------------------------------------------------------------
__global__ void count_kernel(const int* __restrict__ dst, int* __restrict__ cnt, int E) {
    int i = blockIdx.x * blockDim.x + threadIdx.x;
    int stride = gridDim.x * blockDim.x;
    for (; i < E; i += stride) atomicAdd(&cnt[dst[i]], 1);
}

// Single-block scan: wave-shuffle inclusive scan + cross-wave LDS scan.
// 3 barriers per 1024-chunk instead of ~20.
__global__ __launch_bounds__(1024) void scan_kernel(const int* __restrict__ cnt,
        int* __restrict__ rs, int* __restrict__ cur, int T) {
    __shared__ int wsum[16];
    int tid = threadIdx.x;
    int lane = tid & 63, wid = tid >> 6;
    int carry = 0;
    for (int base = 0; base < T; base += 1024) {
        int i = base + tid;
        int v = (i < T) ? cnt[i] : 0;
        // wave-inclusive scan
        int s = v;
        #pragma unroll
        for (int off = 1; off < 64; off <<= 1) {
            int t = __shfl_up(s, off, 64);
            if (lane >= off) s += t;
        }
        if (lane == 63) wsum[wid] = s;
        __syncthreads();
        if (wid == 0) {
            int w = (lane < 16) ? wsum[lane] : 0;
            #pragma unroll
            for (int off = 1; off < 16; off <<= 1) {
                int t = __shfl_up(w, off, 64);
                if (lane >= off) w += t;
            }
            if (lane < 16) wsum[lane] = w;
        }
        __syncthreads();
        int excl = s - v + (wid > 0 ? wsum[wid - 1] : 0) + carry;
        if (i < T) { rs[i] = excl; cur[i] = excl; }
        int total = wsum[15];
        __syncthreads();   // protect wsum before next chunk overwrites it
        carry += total;
    }
    if (tid == 0) rs[T] = carry;
}

__global__ void scatter_kernel(const int* __restrict__ src, const int* __restrict__ dst,
        int* __restrict__ cur, int* __restrict__ ss, int E) {
    int i = blockIdx.x * blockDim.x + threadIdx.x;
    int stride = gridDim.x * blockDim.x;
    for (; i < E; i += stride) {
        int d = dst[i];
        int pos = atomicAdd(&cur[d], 1);
        ss[pos] = src[i];
    }
}

// ---------------------------------------------------------------------------
// Mean aggregation: one wave per target node, coalesced full-row reads.
// F = 512 -> 8 floats/lane (2x float4); F = 256 -> 4 floats/lane (1x float4).
// ---------------------------------------------------------------------------
template <int F>
__global__ void aggregate_kernel(const float* __restrict__ feat, const int* __restrict__ ss,
        const int* __restrict__ rs, float* __restrict__ mean, int T) {
    int gw = (int)((blockIdx.x * (size_t)blockDim.x + threadIdx.x) >> 6);
    int lane = threadIdx.x & 63;
    if (gw >= T) return;
    int j0 = rs[gw], j1 = rs[gw + 1];
    float4 a0 = make_float4(0.f, 0.f, 0.f, 0.f);
    float4 a1 = make_float4(0.f, 0.f, 0.f, 0.f);
    constexpr int PER = F / 64;   // floats per lane
    for (int j = j0; j < j1; ++j) {
        int s = ss[j];
        const float* p = feat + (size_t)s * F + lane * PER;
        float4 v0 = *(const float4*)p;
        a0.x += v0.x; a0.y += v0.y; a0.z += v0.z; a0.w += v0.w;
        if (PER == 8) {
            float4 v1 = *(const float4*)(p + 4);
            a1.x += v1.x; a1.y += v1.y; a1.z += v1.z; a1.w += v1.w;
        }
    }
    int d = j1 - j0;
    float inv = 1.0f / (float)(d > 1 ? d : 1);
    float* o = mean + (size_t)gw * F + lane * PER;
    *(float4*)o = make_float4(a0.x * inv, a0.y * inv, a0.z * inv, a0.w * inv);
    if (PER == 8)
        *(float4*)(o + 4) = make_float4(a1.x * inv, a1.y * inv, a1.z * inv, a1.w * inv);
}

// ---------------------------------------------------------------------------
// GEMM1: h[30000,256] = relu( mean1 @ Wl1^T + x[:30000] @ Wr1^T + bl1 )
// Treated as concat-K GEMM: A_cat[t][k<512]=mean1, else x; W_cat likewise.
// 128x128 tile, BK=16, 256 threads, 8x8 micro-tile, register prefetch.
// ---------------------------------------------------------------------------
__global__ __launch_bounds__(256, 2) void gemm1_kernel(const float* __restrict__ mean1,
        const float* __restrict__ x, const float* __restrict__ Wl,
        const float* __restrict__ Wr, const float* __restrict__ bias,
        float* __restrict__ h) {
    __shared__ float As[16][128];   // [k][row]
    __shared__ float Bs[16][128];   // [k][col]
    int tid = threadIdx.x;
    int brow = blockIdx.x * 128;
    int bcol = blockIdx.y * 128;
    int lrow = tid >> 1;            // 0..127 (row for A, col for B)
    int lkh  = (tid & 1) << 3;      // 0 or 8

    int tx = tid & 15, ty = tid >> 4;

    int arow = min(brow + lrow, T1N - 1);   // clamp tail rows (stores guarded)
    const float* Am = mean1 + (size_t)arow * FIN;
    const float* Ax = x + (size_t)arow * FIN;
    const float* Bl = Wl + (size_t)(bcol + lrow) * FIN;
    const float* Br = Wr + (size_t)(bcol + lrow) * FIN;

    float acc[8][8] = {};

    // prefetch k-tile 0 (always mean/Wl half)
    float4 pa0 = *(const float4*)(Am + lkh);
    float4 pa1 = *(const float4*)(Am + lkh + 4);
    float4 pb0 = *(const float4*)(Bl + lkh);
    float4 pb1 = *(const float4*)(Bl + lkh + 4);

    for (int kt = 0; kt < 2 * FIN; kt += 16) {
        __syncthreads();   // previous compute done before overwrite
        As[lkh + 0][lrow] = pa0.x; As[lkh + 1][lrow] = pa0.y;
        As[lkh + 2][lrow] = pa0.z; As[lkh + 3][lrow] = pa0.w;
        As[lkh + 4][lrow] = pa1.x; As[lkh + 5][lrow] = pa1.y;
        As[lkh + 6][lrow] = pa1.z; As[lkh + 7][lrow] = pa1.w;
        Bs[lkh + 0][lrow] = pb0.x; Bs[lkh + 1][lrow] = pb0.y;
        Bs[lkh + 2][lrow] = pb0.z; Bs[lkh + 3][lrow] = pb0.w;
        Bs[lkh + 4][lrow] = pb1.x; Bs[lkh + 5][lrow] = pb1.y;
        Bs[lkh + 6][lrow] = pb1.z; Bs[lkh + 7][lrow] = pb1.w;
        __syncthreads();

        int kn = kt + 16;
        if (kn < 2 * FIN) {   // prefetch next tile while computing this one
            const float* Ab = (kn < FIN) ? (Am + kn) : (Ax + (kn - FIN));
            const float* Bb = (kn < FIN) ? (Bl + kn) : (Br + (kn - FIN));
            pa0 = *(const float4*)(Ab + lkh);
            pa1 = *(const float4*)(Ab + lkh + 4);
            pb0 = *(const float4*)(Bb + lkh);
            pb1 = *(const float4*)(Bb + lkh + 4);
        }

        #pragma unroll
        for (int kk = 0; kk < 16; ++kk) {
            float4 a0 = *(const float4*)&As[kk][ty * 8];
            float4 a1 = *(const float4*)&As[kk][ty * 8 + 4];
            float4 b0 = *(const float4*)&Bs[kk][tx * 8];
            float4 b1 = *(const float4*)&Bs[kk][tx * 8 + 4];
            float a[8] = {a0.x, a0.y, a0.z, a0.w, a1.x, a1.y, a1.z, a1.w};
            float b[8] = {b0.x, b0.y, b0.z, b0.w, b1.x, b1.y, b1.z, b1.w};
            #pragma unroll
            for (int i = 0; i < 8; ++i)
                #pragma unroll
                for (int j = 0; j < 8; ++j)
                    acc[i][j] = fmaf(a[i], b[j], acc[i][j]);
        }
    }

    // epilogue: bias + relu, vectorized stores (staged via a proper array —
    // previous version wrote past a float4, which was UB)
    #pragma unroll
    for (int i = 0; i < 8; ++i) {
        int r = brow + ty * 8 + i;
        if (r < T1N) {
            float* hp = h + (size_t)r * FHID + bcol + tx * 8;
            float ov[8];
            #pragma unroll
            for (int j = 0; j < 8; ++j) {
                float v = acc[i][j] + bias[bcol + tx * 8 + j];
                ov[j] = v > 0.f ? v : 0.f;
            }
            *(float4*)hp       = make_float4(ov[0], ov[1], ov[2], ov[3]);
            *(float4*)(hp + 4) = make_float4(ov[4], ov[5], ov[6], ov[7]);
        }
    }
}

// ---------------------------------------------------------------------------
// GEMM2 + log_softmax fused: out[8192,20]
// One wave per row; weights staged in LDS; wave shuffle-reduce over K=256.
// ---------------------------------------------------------------------------
__global__ __launch_bounds__(256) void gemm2_lsm_kernel(const float* __restrict__ mean2,
        const float* __restrict__ h, const float* __restrict__ Wl,
        const float* __restrict__ Wr, const float* __restrict__ bias,
        float* __restrict__ out) {
    __shared__ float Wls[FOUT * FHID];
    __shared__ float Wrs[FOUT * FHID];
    int tid = threadIdx.x;
    for (int i = tid; i < FOUT * FHID / 4; i += 256) {
        ((float4*)Wls)[i] = ((const float4*)Wl)[i];
        ((float4*)Wrs)[i] = ((const float4*)Wr)[i];
    }
    __syncthreads();

    int row = blockIdx.x * 4 + (tid >> 6);
    int lane = tid & 63;
    if (row >= T2N) return;

    float acc[FOUT];
    #pragma unroll
    for (int o = 0; o < FOUT; ++o) acc[o] = 0.f;

    const float* mrow = mean2 + (size_t)row * FHID;
    const float* hrow = h + (size_t)row * FHID;
    #pragma unroll
    for (int kk = 0; kk < 4; ++kk) {
        int k = lane + kk * 64;
        float m = mrow[k];
        float hr = hrow[k];
        #pragma unroll
        for (int o = 0; o < FOUT; ++o)
            acc[o] = fmaf(m, Wls[o * FHID + k], fmaf(hr, Wrs[o * FHID + k], acc[o]));
    }
    #pragma unroll
    for (int o = 0; o < FOUT; ++o)
        #pragma unroll
        for (int off = 32; off > 0; off >>= 1)
            acc[o] += __shfl_down(acc[o], off, 64);

    if (lane == 0) {
        float mx = -1e30f;
        #pragma unroll
        for (int o = 0; o < FOUT; ++o) {
            acc[o] += bias[o];
            mx = fmaxf(mx, acc[o]);
        }
        float s = 0.f;
        #pragma unroll
        for (int o = 0; o < FOUT; ++o) s += expf(acc[o] - mx);
        float lse = mx + logf(s);
        float* op = out + (size_t)row * FOUT;
        #pragma unroll
        for (int o = 0; o < FOUT; ++o) op[o] = acc[o] - lse;
    }
}

// ---------------------------------------------------------------------------
extern "C" void kernel_launch(void* const* d_in, const int* in_sizes, int n_in,
                              void* d_out, int out_size, void* d_ws, size_t ws_size,
                              hipStream_t stream) {
    const float* x   = (const float*)d_in[0];
    const int* src1  = (const int*)d_in[1];
    const int* dst1  = (const int*)d_in[2];
    const int* src2  = (const int*)d_in[3];
    const int* dst2  = (const int*)d_in[4];
    const float* Wl1 = (const float*)d_in[5];
    const float* bl1 = (const float*)d_in[6];
    const float* Wr1 = (const float*)d_in[7];
    const float* Wl2 = (const float*)d_in[8];
    const float* bl2 = (const float*)d_in[9];
    const float* Wr2 = (const float*)d_in[10];
    int E1 = in_sizes[1];
    int E2 = in_sizes[3];

    // workspace carve-up (~103 MB total)
    char* p = (char*)d_ws;
    auto alloc = [&](size_t bytes) {
        char* r = p;
        p += (bytes + 255) & ~(size_t)255;
        return r;
    };
    float* mean1 = (float*)alloc((size_t)T1N * FIN * 4);
    float* hbuf  = (float*)alloc((size_t)T1N * FHID * 4);
    float* mean2 = (float*)alloc((size_t)T2N * FHID * 4);
    int* cnt1 = (int*)alloc((size_t)T1N * 4);
    int* rs1  = (int*)alloc((size_t)(T1N + 1) * 4);
    int* cur1 = (int*)alloc((size_t)T1N * 4);
    int* ss1  = (int*)alloc((size_t)E1 * 4);
    int* cnt2 = (int*)alloc((size_t)T2N * 4);
    int* rs2  = (int*)alloc((size_t)(T2N + 1) * 4);
    int* cur2 = (int*)alloc((size_t)T2N * 4);
    int* ss2  = (int*)alloc((size_t)E2 * 4);

    hipMemsetAsync(cnt1, 0, (size_t)T1N * 4, stream);
    hipMemsetAsync(cnt2, 0, (size_t)T2N * 4, stream);

    count_kernel<<<512, 256, 0, stream>>>(dst1, cnt1, E1);
    count_kernel<<<256, 256, 0, stream>>>(dst2, cnt2, E2);
    scan_kernel<<<1, 1024, 0, stream>>>(cnt1, rs1, cur1, T1N);
    scan_kernel<<<1, 1024, 0, stream>>>(cnt2, rs2, cur2, T2N);
    scatter_kernel<<<512, 256, 0, stream>>>(src1, dst1, cur1, ss1, E1);
    scatter_kernel<<<256, 256, 0, stream>>>(src2, dst2, cur2, ss2, E2);

    // layer 1
    aggregate_kernel<FIN><<<(T1N * 64 + 255) / 256, 256, 0, stream>>>(x, ss1, rs1, mean1, T1N);
    dim3 g1((T1N + 127) / 128, FHID / 128);
    gemm1_kernel<<<g1, 256, 0, stream>>>(mean1, x, Wl1, Wr1, bl1, hbuf);

    // layer 2
    aggregate_kernel<FHID><<<(T2N * 64 + 255) / 256, 256, 0, stream>>>(hbuf, ss2, rs2, mean2, T2N);
    gemm2_lsm_kernel<<<T2N / 4, 256, 0, stream>>>(mean2, hbuf, Wl2, Wr2, bl2, (float*)d_out);
}

// Round 3
// 686.395 us; speedup vs baseline: 1.2021x; 1.2021x over previous
//
#include <hip/hip_runtime.h>
#include <math.h>

// Problem constants (match reference)
constexpr int T1N  = 30000;
constexpr int T2N  = 8192;
constexpr int FIN  = 512;
constexpr int FHID = 256;
constexpr int FOUT = 20;

typedef short bf16x8 __attribute__((ext_vector_type(8)));
typedef float f32x4  __attribute__((ext_vector_type(4)));

__device__ __forceinline__ short f2bf(float f) {
    unsigned u = __float_as_uint(f);
    u += 0x7fff + ((u >> 16) & 1);     // RNE; inputs are finite normals
    return (short)(u >> 16);
}

__device__ __forceinline__ void gload16(const void* g, void* l) {
    __builtin_amdgcn_global_load_lds(
        (const __attribute__((address_space(1))) void*)g,
        (__attribute__((address_space(3))) void*)l, 16, 0, 0);
}

// ---------------------------------------------------------------------------
// CSR build: count -> exclusive scan -> bucket scatter
// ---------------------------------------------------------------------------
__global__ void count_kernel(const int* __restrict__ dst, int* __restrict__ cnt, int E) {
    int i = blockIdx.x * blockDim.x + threadIdx.x;
    int stride = gridDim.x * blockDim.x;
    for (; i < E; i += stride) atomicAdd(&cnt[dst[i]], 1);
}

__global__ __launch_bounds__(1024) void scan_kernel(const int* __restrict__ cnt,
        int* __restrict__ rs, int* __restrict__ cur, int T) {
    __shared__ int wsum[16];
    int tid = threadIdx.x;
    int lane = tid & 63, wid = tid >> 6;
    int carry = 0;
    for (int base = 0; base < T; base += 1024) {
        int i = base + tid;
        int v = (i < T) ? cnt[i] : 0;
        int s = v;
        #pragma unroll
        for (int off = 1; off < 64; off <<= 1) {
            int t = __shfl_up(s, off, 64);
            if (lane >= off) s += t;
        }
        if (lane == 63) wsum[wid] = s;
        __syncthreads();
        if (wid == 0) {
            int w = (lane < 16) ? wsum[lane] : 0;
            #pragma unroll
            for (int off = 1; off < 16; off <<= 1) {
                int t = __shfl_up(w, off, 64);
                if (lane >= off) w += t;
            }
            if (lane < 16) wsum[lane] = w;
        }
        __syncthreads();
        int excl = s - v + (wid > 0 ? wsum[wid - 1] : 0) + carry;
        if (i < T) { rs[i] = excl; cur[i] = excl; }
        int total = wsum[15];
        __syncthreads();
        carry += total;
    }
    if (tid == 0) rs[T] = carry;
}

__global__ void scatter_kernel(const int* __restrict__ src, const int* __restrict__ dst,
        int* __restrict__ cur, int* __restrict__ ss, int E) {
    int i = blockIdx.x * blockDim.x + threadIdx.x;
    int stride = gridDim.x * blockDim.x;
    for (; i < E; i += stride) {
        int d = dst[i];
        int pos = atomicAdd(&cur[d], 1);
        ss[pos] = src[i];
    }
}

// ---------------------------------------------------------------------------
// Conversions for bf16 layer-1 GEMM
// ---------------------------------------------------------------------------
// x[:T1N] fp32 -> A[r][512..1023] bf16 (A row stride 1024)
__global__ void convert_x_kernel(const float* __restrict__ x, short* __restrict__ A) {
    size_t i = ((size_t)blockIdx.x * blockDim.x + threadIdx.x) * 8;
    if (i >= (size_t)T1N * FIN) return;
    int r = (int)(i >> 9);
    int k = (int)(i & 511);
    const float* p = x + (size_t)r * FIN + k;
    float4 v0 = *(const float4*)p;
    float4 v1 = *(const float4*)(p + 4);
    bf16x8 o;
    o[0] = f2bf(v0.x); o[1] = f2bf(v0.y); o[2] = f2bf(v0.z); o[3] = f2bf(v0.w);
    o[4] = f2bf(v1.x); o[5] = f2bf(v1.y); o[6] = f2bf(v1.z); o[7] = f2bf(v1.w);
    *(bf16x8*)(A + (size_t)r * 1024 + 512 + k) = o;
}

// Wcat[n][0..511]=Wl1[n][:], Wcat[n][512..1023]=Wr1[n][:]  (bf16)
__global__ void convert_w_kernel(const float* __restrict__ Wl, const float* __restrict__ Wr,
        short* __restrict__ Wcat) {
    int i = (blockIdx.x * blockDim.x + threadIdx.x) * 8;
    if (i >= FHID * 1024) return;
    int n = i >> 10;
    int k = i & 1023;
    const float* sp = (k < 512) ? (Wl + (size_t)n * FIN + k) : (Wr + (size_t)n * FIN + (k - 512));
    float4 v0 = *(const float4*)sp;
    float4 v1 = *(const float4*)(sp + 4);
    bf16x8 o;
    o[0] = f2bf(v0.x); o[1] = f2bf(v0.y); o[2] = f2bf(v0.z); o[3] = f2bf(v0.w);
    o[4] = f2bf(v1.x); o[5] = f2bf(v1.y); o[6] = f2bf(v1.z); o[7] = f2bf(v1.w);
    *(bf16x8*)(Wcat + (size_t)n * 1024 + k) = o;
}

// ---------------------------------------------------------------------------
// Mean aggregation: one wave per target node, coalesced full-row reads.
// OT=short -> bf16 output (layer 1 writes into A buffer, stride 1024)
// OT=float -> fp32 output (layer 2)
// ---------------------------------------------------------------------------
template <int F, typename OT, int OSTR>
__global__ void aggregate_kernel(const float* __restrict__ feat, const int* __restrict__ ss,
        const int* __restrict__ rs, OT* __restrict__ mean, int T) {
    int gw = (int)((blockIdx.x * (size_t)blockDim.x + threadIdx.x) >> 6);
    int lane = threadIdx.x & 63;
    if (gw >= T) return;
    int j0 = rs[gw], j1 = rs[gw + 1];
    float4 a0 = make_float4(0.f, 0.f, 0.f, 0.f);
    float4 a1 = make_float4(0.f, 0.f, 0.f, 0.f);
    constexpr int PER = F / 64;   // floats per lane (8 or 4)
    for (int j = j0; j < j1; ++j) {
        int s = ss[j];
        const float* p = feat + (size_t)s * F + lane * PER;
        float4 v0 = *(const float4*)p;
        a0.x += v0.x; a0.y += v0.y; a0.z += v0.z; a0.w += v0.w;
        if (PER == 8) {
            float4 v1 = *(const float4*)(p + 4);
            a1.x += v1.x; a1.y += v1.y; a1.z += v1.z; a1.w += v1.w;
        }
    }
    int d = j1 - j0;
    float inv = 1.0f / (float)(d > 1 ? d : 1);
    if constexpr (sizeof(OT) == 2) {
        // bf16 out: 8 elems/lane packed 16B store
        bf16x8 o;
        o[0] = f2bf(a0.x * inv); o[1] = f2bf(a0.y * inv);
        o[2] = f2bf(a0.z * inv); o[3] = f2bf(a0.w * inv);
        o[4] = f2bf(a1.x * inv); o[5] = f2bf(a1.y * inv);
        o[6] = f2bf(a1.z * inv); o[7] = f2bf(a1.w * inv);
        *(bf16x8*)(mean + (size_t)gw * OSTR + lane * PER) = o;
    } else {
        float* o = (float*)(mean + (size_t)gw * OSTR + lane * PER);
        *(float4*)o = make_float4(a0.x * inv, a0.y * inv, a0.z * inv, a0.w * inv);
        if (PER == 8)
            *(float4*)(o + 4) = make_float4(a1.x * inv, a1.y * inv, a1.z * inv, a1.w * inv);
    }
}

// ---------------------------------------------------------------------------
// GEMM1 (bf16 MFMA): h[30000,256] = relu(A[30000,1024] @ Wcat[256,1024]^T + bl1)
// A = [mean1 | x], Wcat = [Wl1 | Wr1]. 128x128 tile, BK=32, 4 waves (2x2),
// each wave 64x64 = 4x4 frags of 16x16x32. global_load_lds staging with
// slot-XOR swizzle (linear LDS dest + pre-swizzled global src + swizzled read).
// ---------------------------------------------------------------------------
__global__ __launch_bounds__(256, 2) void gemm1_mfma(
        const short* __restrict__ A, const short* __restrict__ W,
        const float* __restrict__ bias, float* __restrict__ h) {
    __shared__ short As[128 * 32];   // 8KB: chunk c=(row*4+slot), 16B chunks
    __shared__ short Bs[128 * 32];   // 8KB
    int tid = threadIdx.x;
    int wid = tid >> 6, lane = tid & 63;
    int brow = blockIdx.x * 128, bcol = blockIdx.y * 128;
    int wr = (wid >> 1) * 64, wc = (wid & 1) * 64;

    f32x4 acc[4][4] = {};

    int kgrp = lane >> 4;        // 0..3: which 8-wide k slot this lane reads
    int r16 = lane & 15;

    for (int kt = 0; kt < 1024; kt += 32) {
        // stage: each wave 2 chunks of 1KB for A and B each
        #pragma unroll
        for (int c2 = 0; c2 < 2; ++c2) {
            int q = wid + c2 * 4;            // 1KB chunk id 0..7
            int c = q * 64 + lane;           // 16B chunk id 0..511
            int row = c >> 2;                // 0..127
            int sl = (c & 3) ^ (row & 3);    // pre-swizzled global slot
            int gr = brow + row; if (gr > T1N - 1) gr = T1N - 1;
            gload16(A + (size_t)gr * 1024 + kt + sl * 8, (char*)As + q * 1024);
            gload16(W + (size_t)(bcol + row) * 1024 + kt + sl * 8, (char*)Bs + q * 1024);
        }
        __syncthreads();   // drains vmcnt -> tiles complete

        bf16x8 af[4], bfr[4];
        #pragma unroll
        for (int m = 0; m < 4; ++m) {
            int row = wr + m * 16 + r16;
            int sl = kgrp ^ (row & 3);
            af[m] = *(const bf16x8*)((const char*)As + row * 64 + sl * 16);
        }
        #pragma unroll
        for (int n = 0; n < 4; ++n) {
            int row = wc + n * 16 + r16;
            int sl = kgrp ^ (row & 3);
            bfr[n] = *(const bf16x8*)((const char*)Bs + row * 64 + sl * 16);
        }
        #pragma unroll
        for (int m = 0; m < 4; ++m)
            #pragma unroll
            for (int n = 0; n < 4; ++n)
                acc[m][n] = __builtin_amdgcn_mfma_f32_16x16x32_bf16(
                        af[m], bfr[n], acc[m][n], 0, 0, 0);
        __syncthreads();   // before next overwrite
    }

    // epilogue: C/D layout col=lane&15, row=(lane>>4)*4+reg  [m89]
    int g4 = lane >> 4;
    #pragma unroll
    for (int n = 0; n < 4; ++n) {
        int col = bcol + wc + n * 16 + r16;
        float bv = bias[col];
        #pragma unroll
        for (int m = 0; m < 4; ++m) {
            #pragma unroll
            for (int r = 0; r < 4; ++r) {
                int row = brow + wr + m * 16 + g4 * 4 + r;
                if (row < T1N) {
                    float v = acc[m][n][r] + bv;
                    h[(size_t)row * FHID + col] = v > 0.f ? v : 0.f;
                }
            }
        }
    }
}

// ---------------------------------------------------------------------------
// GEMM2 + log_softmax fused: out[8192,20] (fp32)
// ---------------------------------------------------------------------------
__global__ __launch_bounds__(256) void gemm2_lsm_kernel(const float* __restrict__ mean2,
        const float* __restrict__ h, const float* __restrict__ Wl,
        const float* __restrict__ Wr, const float* __restrict__ bias,
        float* __restrict__ out) {
    __shared__ float Wls[FOUT * FHID];
    __shared__ float Wrs[FOUT * FHID];
    int tid = threadIdx.x;
    for (int i = tid; i < FOUT * FHID / 4; i += 256) {
        ((float4*)Wls)[i] = ((const float4*)Wl)[i];
        ((float4*)Wrs)[i] = ((const float4*)Wr)[i];
    }
    __syncthreads();

    int row = blockIdx.x * 4 + (tid >> 6);
    int lane = tid & 63;
    if (row >= T2N) return;

    float acc[FOUT];
    #pragma unroll
    for (int o = 0; o < FOUT; ++o) acc[o] = 0.f;

    const float* mrow = mean2 + (size_t)row * FHID;
    const float* hrow = h + (size_t)row * FHID;
    #pragma unroll
    for (int kk = 0; kk < 4; ++kk) {
        int k = lane + kk * 64;
        float m = mrow[k];
        float hr = hrow[k];
        #pragma unroll
        for (int o = 0; o < FOUT; ++o)
            acc[o] = fmaf(m, Wls[o * FHID + k], fmaf(hr, Wrs[o * FHID + k], acc[o]));
    }
    #pragma unroll
    for (int o = 0; o < FOUT; ++o)
        #pragma unroll
        for (int off = 32; off > 0; off >>= 1)
            acc[o] += __shfl_down(acc[o], off, 64);

    if (lane == 0) {
        float mx = -1e30f;
        #pragma unroll
        for (int o = 0; o < FOUT; ++o) {
            acc[o] += bias[o];
            mx = fmaxf(mx, acc[o]);
        }
        float s = 0.f;
        #pragma unroll
        for (int o = 0; o < FOUT; ++o) s += expf(acc[o] - mx);
        float lse = mx + logf(s);
        float* op = out + (size_t)row * FOUT;
        #pragma unroll
        for (int o = 0; o < FOUT; ++o) op[o] = acc[o] - lse;
    }
}

// ---------------------------------------------------------------------------
extern "C" void kernel_launch(void* const* d_in, const int* in_sizes, int n_in,
                              void* d_out, int out_size, void* d_ws, size_t ws_size,
                              hipStream_t stream) {
    const float* x   = (const float*)d_in[0];
    const int* src1  = (const int*)d_in[1];
    const int* dst1  = (const int*)d_in[2];
    const int* src2  = (const int*)d_in[3];
    const int* dst2  = (const int*)d_in[4];
    const float* Wl1 = (const float*)d_in[5];
    const float* bl1 = (const float*)d_in[6];
    const float* Wr1 = (const float*)d_in[7];
    const float* Wl2 = (const float*)d_in[8];
    const float* bl2 = (const float*)d_in[9];
    const float* Wr2 = (const float*)d_in[10];
    int E1 = in_sizes[1];
    int E2 = in_sizes[3];

    // workspace carve-up (~103 MB total)
    char* p = (char*)d_ws;
    auto alloc = [&](size_t bytes) {
        char* r = p;
        p += (bytes + 255) & ~(size_t)255;
        return r;
    };
    short* Abuf  = (short*)alloc((size_t)T1N * 1024 * 2);  // [mean1 | x] bf16
    short* Wcat  = (short*)alloc((size_t)FHID * 1024 * 2); // [Wl1 | Wr1] bf16
    float* hbuf  = (float*)alloc((size_t)T1N * FHID * 4);
    float* mean2 = (float*)alloc((size_t)T2N * FHID * 4);
    int* cnt1 = (int*)alloc((size_t)T1N * 4);
    int* rs1  = (int*)alloc((size_t)(T1N + 1) * 4);
    int* cur1 = (int*)alloc((size_t)T1N * 4);
    int* ss1  = (int*)alloc((size_t)E1 * 4);
    int* cnt2 = (int*)alloc((size_t)T2N * 4);
    int* rs2  = (int*)alloc((size_t)(T2N + 1) * 4);
    int* cur2 = (int*)alloc((size_t)T2N * 4);
    int* ss2  = (int*)alloc((size_t)E2 * 4);

    hipMemsetAsync(cnt1, 0, (size_t)T1N * 4, stream);
    hipMemsetAsync(cnt2, 0, (size_t)T2N * 4, stream);

    count_kernel<<<512, 256, 0, stream>>>(dst1, cnt1, E1);
    count_kernel<<<256, 256, 0, stream>>>(dst2, cnt2, E2);
    scan_kernel<<<1, 1024, 0, stream>>>(cnt1, rs1, cur1, T1N);
    scan_kernel<<<1, 1024, 0, stream>>>(cnt2, rs2, cur2, T2N);
    scatter_kernel<<<512, 256, 0, stream>>>(src1, dst1, cur1, ss1, E1);
    scatter_kernel<<<256, 256, 0, stream>>>(src2, dst2, cur2, ss2, E2);

    // bf16 conversions (independent of CSR build)
    convert_w_kernel<<<(FHID * 1024 / 8 + 255) / 256, 256, 0, stream>>>(Wl1, Wr1, Wcat);
    convert_x_kernel<<<(int)(((size_t)T1N * FIN / 8 + 255) / 256), 256, 0, stream>>>(x, Abuf);

    // layer 1
    aggregate_kernel<FIN, short, 1024>
        <<<(T1N * 64 + 255) / 256, 256, 0, stream>>>(x, ss1, rs1, Abuf, T1N);
    dim3 g1((T1N + 127) / 128, FHID / 128);
    gemm1_mfma<<<g1, 256, 0, stream>>>(Abuf, Wcat, bl1, hbuf);

    // layer 2 (fp32 throughout)
    aggregate_kernel<FHID, float, FHID>
        <<<(T2N * 64 + 255) / 256, 256, 0, stream>>>(hbuf, ss2, rs2, mean2, T2N);
    gemm2_lsm_kernel<<<T2N / 4, 256, 0, stream>>>(mean2, hbuf, Wl2, Wr2, bl2, (float*)d_out);
}

// Round 4
// 685.229 us; speedup vs baseline: 1.2041x; 1.0017x over previous
//
#include <hip/hip_runtime.h>
#include <math.h>

// Problem constants (match reference)
constexpr int T1N  = 30000;
constexpr int T2N  = 8192;
constexpr int FIN  = 512;
constexpr int FHID = 256;
constexpr int FOUT = 20;

typedef short bf16x8 __attribute__((ext_vector_type(8)));
typedef float f32x4  __attribute__((ext_vector_type(4)));

__device__ __forceinline__ short f2bf(float f) {
    unsigned u = __float_as_uint(f);
    u += 0x7fff + ((u >> 16) & 1);     // RNE; inputs are finite normals
    return (short)(u >> 16);
}
__device__ __forceinline__ float bf2f(short s) {
    return __uint_as_float(((unsigned)(unsigned short)s) << 16);
}

__device__ __forceinline__ void gload16(const void* g, void* l) {
    __builtin_amdgcn_global_load_lds(
        (const __attribute__((address_space(1))) void*)g,
        (__attribute__((address_space(3))) void*)l, 16, 0, 0);
}

// ---------------------------------------------------------------------------
// CSR build: count -> exclusive scan -> bucket scatter
// ---------------------------------------------------------------------------
__global__ void count_kernel(const int* __restrict__ dst, int* __restrict__ cnt, int E) {
    int i = blockIdx.x * blockDim.x + threadIdx.x;
    int stride = gridDim.x * blockDim.x;
    for (; i < E; i += stride) atomicAdd(&cnt[dst[i]], 1);
}

// Single-block scan, int4 per thread (4096 elems/chunk), wave-shuffle scans.
__global__ __launch_bounds__(1024) void scan_kernel(const int* __restrict__ cnt,
        int* __restrict__ rs, int* __restrict__ cur, int T) {
    __shared__ int wsum[16];
    int tid = threadIdx.x;
    int lane = tid & 63, wid = tid >> 6;
    int carry = 0;
    for (int base = 0; base < T; base += 4096) {
        int i = base + tid * 4;
        int4 v = make_int4(0, 0, 0, 0);
        if (i + 3 < T) v = *(const int4*)(cnt + i);
        else {
            if (i     < T) v.x = cnt[i];
            if (i + 1 < T) v.y = cnt[i + 1];
            if (i + 2 < T) v.z = cnt[i + 2];
            if (i + 3 < T) v.w = cnt[i + 3];
        }
        int tsum = v.x + v.y + v.z + v.w;
        int s = tsum;
        #pragma unroll
        for (int off = 1; off < 64; off <<= 1) {
            int t = __shfl_up(s, off, 64);
            if (lane >= off) s += t;
        }
        if (lane == 63) wsum[wid] = s;
        __syncthreads();
        if (wid == 0) {
            int w = (lane < 16) ? wsum[lane] : 0;
            #pragma unroll
            for (int off = 1; off < 16; off <<= 1) {
                int t = __shfl_up(w, off, 64);
                if (lane >= off) w += t;
            }
            if (lane < 16) wsum[lane] = w;
        }
        __syncthreads();
        int e0 = s - tsum + (wid > 0 ? wsum[wid - 1] : 0) + carry;
        int e1 = e0 + v.x, e2 = e1 + v.y, e3 = e2 + v.z;
        if (i + 3 < T) {
            *(int4*)(rs + i)  = make_int4(e0, e1, e2, e3);
            *(int4*)(cur + i) = make_int4(e0, e1, e2, e3);
        } else {
            if (i     < T) { rs[i]     = e0; cur[i]     = e0; }
            if (i + 1 < T) { rs[i + 1] = e1; cur[i + 1] = e1; }
            if (i + 2 < T) { rs[i + 2] = e2; cur[i + 2] = e2; }
        }
        int total = wsum[15];
        __syncthreads();
        carry += total;
    }
    if (tid == 0) rs[T] = carry;
}

__global__ void scatter_kernel(const int* __restrict__ src, const int* __restrict__ dst,
        int* __restrict__ cur, int* __restrict__ ss, int E) {
    int i = blockIdx.x * blockDim.x + threadIdx.x;
    int stride = gridDim.x * blockDim.x;
    for (; i < E; i += stride) {
        int d = dst[i];
        int pos = atomicAdd(&cur[d], 1);
        ss[pos] = src[i];
    }
}

// ---------------------------------------------------------------------------
// Full x -> bf16 (all N rows): xbf[150000][512]. Gather then reads bf16 rows
// (154 MB footprint -> L3-resident) and GEMM1 reads its x-half from here.
// ---------------------------------------------------------------------------
__global__ void convert_x_full(const float* __restrict__ x, short* __restrict__ xbf, long n8) {
    long i = ((long)blockIdx.x * blockDim.x + threadIdx.x);
    if (i >= n8) return;
    const float* p = x + i * 8;
    float4 v0 = *(const float4*)p;
    float4 v1 = *(const float4*)(p + 4);
    bf16x8 o;
    o[0] = f2bf(v0.x); o[1] = f2bf(v0.y); o[2] = f2bf(v0.z); o[3] = f2bf(v0.w);
    o[4] = f2bf(v1.x); o[5] = f2bf(v1.y); o[6] = f2bf(v1.z); o[7] = f2bf(v1.w);
    *(bf16x8*)(xbf + i * 8) = o;
}

// Wcat[n][0..511]=Wl1[n][:], Wcat[n][512..1023]=Wr1[n][:]  (bf16)
__global__ void convert_w_kernel(const float* __restrict__ Wl, const float* __restrict__ Wr,
        short* __restrict__ Wcat) {
    int i = (blockIdx.x * blockDim.x + threadIdx.x) * 8;
    if (i >= FHID * 1024) return;
    int n = i >> 10;
    int k = i & 1023;
    const float* sp = (k < 512) ? (Wl + (size_t)n * FIN + k) : (Wr + (size_t)n * FIN + (k - 512));
    float4 v0 = *(const float4*)sp;
    float4 v1 = *(const float4*)(sp + 4);
    bf16x8 o;
    o[0] = f2bf(v0.x); o[1] = f2bf(v0.y); o[2] = f2bf(v0.z); o[3] = f2bf(v0.w);
    o[4] = f2bf(v1.x); o[5] = f2bf(v1.y); o[6] = f2bf(v1.z); o[7] = f2bf(v1.w);
    *(bf16x8*)(Wcat + (size_t)n * 1024 + k) = o;
}

// ---------------------------------------------------------------------------
// Aggregation L1: gather bf16 rows (512), mean in fp32, write bf16 [T1N][512].
// One wave per target node; 16B (8 bf16) per lane.
// ---------------------------------------------------------------------------
__global__ void agg1_kernel(const short* __restrict__ xbf, const int* __restrict__ ss,
        const int* __restrict__ rs, short* __restrict__ meanbf, int T) {
    int gw = (int)((blockIdx.x * (size_t)blockDim.x + threadIdx.x) >> 6);
    int lane = threadIdx.x & 63;
    if (gw >= T) return;
    int j0 = rs[gw], j1 = rs[gw + 1];
    float a[8] = {};
    for (int j = j0; j < j1; ++j) {
        int s = ss[j];
        bf16x8 v = *(const bf16x8*)(xbf + (size_t)s * FIN + lane * 8);
        #pragma unroll
        for (int q = 0; q < 8; ++q) a[q] += bf2f(v[q]);
    }
    int d = j1 - j0;
    float inv = 1.0f / (float)(d > 1 ? d : 1);
    bf16x8 o;
    #pragma unroll
    for (int q = 0; q < 8; ++q) o[q] = f2bf(a[q] * inv);
    *(bf16x8*)(meanbf + (size_t)gw * FIN + lane * 8) = o;
}

// Aggregation L2: gather fp32 rows (256), mean fp32, write fp32 [T2N][256].
__global__ void agg2_kernel(const float* __restrict__ feat, const int* __restrict__ ss,
        const int* __restrict__ rs, float* __restrict__ mean, int T) {
    int gw = (int)((blockIdx.x * (size_t)blockDim.x + threadIdx.x) >> 6);
    int lane = threadIdx.x & 63;
    if (gw >= T) return;
    int j0 = rs[gw], j1 = rs[gw + 1];
    float4 a = make_float4(0.f, 0.f, 0.f, 0.f);
    for (int j = j0; j < j1; ++j) {
        int s = ss[j];
        float4 v = *(const float4*)(feat + (size_t)s * FHID + lane * 4);
        a.x += v.x; a.y += v.y; a.z += v.z; a.w += v.w;
    }
    int d = j1 - j0;
    float inv = 1.0f / (float)(d > 1 ? d : 1);
    *(float4*)(mean + (size_t)gw * FHID + lane * 4) =
        make_float4(a.x * inv, a.y * inv, a.z * inv, a.w * inv);
}

// ---------------------------------------------------------------------------
// GEMM1 (bf16 MFMA): h[30000,256] = relu([mean|x] @ [Wl1|Wr1]^T + bl1)
// A-halves from meanbf / xbf (row stride 512); W from Wcat (stride 1024).
// 128x128 tile, BK=32, 4 waves (2x2), 2-phase double-buffered LDS
// (stage next while computing current; one barrier per iter).
// Slot swizzle rx=(row^(row>>2))&3: 2-way LDS read aliasing (free, m136).
// ---------------------------------------------------------------------------
__global__ __launch_bounds__(256, 2) void gemm1_mfma(
        const short* __restrict__ Am, const short* __restrict__ Ax,
        const short* __restrict__ W, const float* __restrict__ bias,
        float* __restrict__ h) {
    __shared__ short As[2][128 * 32];   // 8KB each
    __shared__ short Bs[2][128 * 32];
    int tid = threadIdx.x;
    int wid = tid >> 6, lane = tid & 63;
    int brow = blockIdx.x * 128, bcol = blockIdx.y * 128;
    int wr = (wid >> 1) * 64, wc = (wid & 1) * 64;

    f32x4 acc[4][4] = {};
    int kgrp = lane >> 4;
    int r16 = lane & 15;

    auto stage = [&](int buf, int kt) {
        const short* Abase = (kt < 512) ? Am : Ax;
        int ko = kt & 511;
        #pragma unroll
        for (int c2 = 0; c2 < 2; ++c2) {
            int q = wid + c2 * 4;            // 1KB chunk 0..7
            int c = q * 64 + lane;           // 16B chunk 0..511
            int row = c >> 2;                // 0..127
            int rx = (row ^ (row >> 2)) & 3;
            int sl = (c & 3) ^ rx;           // pre-swizzled global slot
            int gr = brow + row; if (gr > T1N - 1) gr = T1N - 1;
            gload16(Abase + (size_t)gr * 512 + ko + sl * 8, (char*)As[buf] + q * 1024);
            gload16(W + (size_t)(bcol + row) * 1024 + kt + sl * 8, (char*)Bs[buf] + q * 1024);
        }
    };

    stage(0, 0);
    __syncthreads();

    int cur = 0;
    for (int kt = 0; kt < 1024; kt += 32) {
        if (kt + 32 < 1024) stage(cur ^ 1, kt + 32);

        bf16x8 af[4], bfr[4];
        #pragma unroll
        for (int m = 0; m < 4; ++m) {
            int row = wr + m * 16 + r16;
            int sl = kgrp ^ ((row ^ (row >> 2)) & 3);
            af[m] = *(const bf16x8*)((const char*)As[cur] + row * 64 + sl * 16);
        }
        #pragma unroll
        for (int n = 0; n < 4; ++n) {
            int row = wc + n * 16 + r16;
            int sl = kgrp ^ ((row ^ (row >> 2)) & 3);
            bfr[n] = *(const bf16x8*)((const char*)Bs[cur] + row * 64 + sl * 16);
        }
        #pragma unroll
        for (int m = 0; m < 4; ++m)
            #pragma unroll
            for (int n = 0; n < 4; ++n)
                acc[m][n] = __builtin_amdgcn_mfma_f32_16x16x32_bf16(
                        af[m], bfr[n], acc[m][n], 0, 0, 0);

        __syncthreads();   // drains vmcnt (stage done) + lgkm (reads done)
        cur ^= 1;
    }

    // epilogue: C/D layout col=lane&15, row=(lane>>4)*4+reg  [m89]
    int g4 = lane >> 4;
    #pragma unroll
    for (int n = 0; n < 4; ++n) {
        int col = bcol + wc + n * 16 + r16;
        float bv = bias[col];
        #pragma unroll
        for (int m = 0; m < 4; ++m) {
            #pragma unroll
            for (int r = 0; r < 4; ++r) {
                int row = brow + wr + m * 16 + g4 * 4 + r;
                if (row < T1N) {
                    float v = acc[m][n][r] + bv;
                    h[(size_t)row * FHID + col] = v > 0.f ? v : 0.f;
                }
            }
        }
    }
}

// ---------------------------------------------------------------------------
// GEMM2 + log_softmax fused: out[8192,20] (fp32)
// ---------------------------------------------------------------------------
__global__ __launch_bounds__(256) void gemm2_lsm_kernel(const float* __restrict__ mean2,
        const float* __restrict__ h, const float* __restrict__ Wl,
        const float* __restrict__ Wr, const float* __restrict__ bias,
        float* __restrict__ out) {
    __shared__ float Wls[FOUT * FHID];
    __shared__ float Wrs[FOUT * FHID];
    int tid = threadIdx.x;
    for (int i = tid; i < FOUT * FHID / 4; i += 256) {
        ((float4*)Wls)[i] = ((const float4*)Wl)[i];
        ((float4*)Wrs)[i] = ((const float4*)Wr)[i];
    }
    __syncthreads();

    int row = blockIdx.x * 4 + (tid >> 6);
    int lane = tid & 63;
    if (row >= T2N) return;

    float acc[FOUT];
    #pragma unroll
    for (int o = 0; o < FOUT; ++o) acc[o] = 0.f;

    const float* mrow = mean2 + (size_t)row * FHID;
    const float* hrow = h + (size_t)row * FHID;
    #pragma unroll
    for (int kk = 0; kk < 4; ++kk) {
        int k = lane + kk * 64;
        float m = mrow[k];
        float hr = hrow[k];
        #pragma unroll
        for (int o = 0; o < FOUT; ++o)
            acc[o] = fmaf(m, Wls[o * FHID + k], fmaf(hr, Wrs[o * FHID + k], acc[o]));
    }
    #pragma unroll
    for (int o = 0; o < FOUT; ++o)
        #pragma unroll
        for (int off = 32; off > 0; off >>= 1)
            acc[o] += __shfl_down(acc[o], off, 64);

    if (lane == 0) {
        float mx = -1e30f;
        #pragma unroll
        for (int o = 0; o < FOUT; ++o) {
            acc[o] += bias[o];
            mx = fmaxf(mx, acc[o]);
        }
        float s = 0.f;
        #pragma unroll
        for (int o = 0; o < FOUT; ++o) s += expf(acc[o] - mx);
        float lse = mx + logf(s);
        float* op = out + (size_t)row * FOUT;
        #pragma unroll
        for (int o = 0; o < FOUT; ++o) op[o] = acc[o] - lse;
    }
}

// ---------------------------------------------------------------------------
extern "C" void kernel_launch(void* const* d_in, const int* in_sizes, int n_in,
                              void* d_out, int out_size, void* d_ws, size_t ws_size,
                              hipStream_t stream) {
    const float* x   = (const float*)d_in[0];
    const int* src1  = (const int*)d_in[1];
    const int* dst1  = (const int*)d_in[2];
    const int* src2  = (const int*)d_in[3];
    const int* dst2  = (const int*)d_in[4];
    const float* Wl1 = (const float*)d_in[5];
    const float* bl1 = (const float*)d_in[6];
    const float* Wr1 = (const float*)d_in[7];
    const float* Wl2 = (const float*)d_in[8];
    const float* bl2 = (const float*)d_in[9];
    const float* Wr2 = (const float*)d_in[10];
    int E1 = in_sizes[1];
    int E2 = in_sizes[3];
    int N  = in_sizes[0] / FIN;   // 150000

    char* p = (char*)d_ws;
    auto alloc = [&](size_t bytes) {
        char* r = p;
        p += (bytes + 255) & ~(size_t)255;
        return r;
    };
    short* xbf   = (short*)alloc((size_t)N * FIN * 2);     // 154 MB, L3-resident
    short* meanbf= (short*)alloc((size_t)T1N * FIN * 2);   // 31 MB
    short* Wcat  = (short*)alloc((size_t)FHID * 1024 * 2); // 0.5 MB
    float* hbuf  = (float*)alloc((size_t)T1N * FHID * 4);  // 31 MB
    float* mean2 = (float*)alloc((size_t)T2N * FHID * 4);  // 8.4 MB
    int* cnt1 = (int*)alloc((size_t)T1N * 4);
    int* cnt2 = (int*)alloc((size_t)T2N * 4);              // adjacent to cnt1
    int* rs1  = (int*)alloc((size_t)(T1N + 1) * 4);
    int* cur1 = (int*)alloc((size_t)T1N * 4);
    int* ss1  = (int*)alloc((size_t)E1 * 4);
    int* rs2  = (int*)alloc((size_t)(T2N + 1) * 4);
    int* cur2 = (int*)alloc((size_t)T2N * 4);
    int* ss2  = (int*)alloc((size_t)E2 * 4);

    // one memset covers cnt1+cnt2 (allocated contiguously, 256B-padded)
    hipMemsetAsync(cnt1, 0, (size_t)((char*)(cnt2 + T2N) - (char*)cnt1), stream);

    count_kernel<<<512, 256, 0, stream>>>(dst1, cnt1, E1);
    count_kernel<<<256, 256, 0, stream>>>(dst2, cnt2, E2);
    scan_kernel<<<1, 1024, 0, stream>>>(cnt1, rs1, cur1, T1N);
    scan_kernel<<<1, 1024, 0, stream>>>(cnt2, rs2, cur2, T2N);
    scatter_kernel<<<512, 256, 0, stream>>>(src1, dst1, cur1, ss1, E1);
    scatter_kernel<<<256, 256, 0, stream>>>(src2, dst2, cur2, ss2, E2);

    // bf16 conversions
    convert_w_kernel<<<(FHID * 1024 / 8 + 255) / 256, 256, 0, stream>>>(Wl1, Wr1, Wcat);
    long n8 = (long)N * FIN / 8;
    convert_x_full<<<(int)((n8 + 255) / 256), 256, 0, stream>>>(x, xbf, n8);

    // layer 1
    agg1_kernel<<<(T1N * 64 + 255) / 256, 256, 0, stream>>>(xbf, ss1, rs1, meanbf, T1N);
    dim3 g1((T1N + 127) / 128, FHID / 128);
    gemm1_mfma<<<g1, 256, 0, stream>>>(meanbf, xbf, Wcat, bl1, hbuf);

    // layer 2 (fp32 throughout)
    agg2_kernel<<<(T2N * 64 + 255) / 256, 256, 0, stream>>>(hbuf, ss2, rs2, mean2, T2N);
    gemm2_lsm_kernel<<<T2N / 4, 256, 0, stream>>>(mean2, hbuf, Wl2, Wr2, bl2, (float*)d_out);
}